// Round 1
// baseline (523.520 us; speedup 1.0000x reference)
//
#include <hip/hip_runtime.h>
#include <hip/hip_bf16.h>

#define NN 50000
#define NE 800000
#define DNODE 64
#define HD 128

typedef __attribute__((ext_vector_type(8)))  short bf16x8;   // 8 bf16 (4 VGPRs)
typedef __attribute__((ext_vector_type(16))) float f32x16;   // MFMA C/D
typedef __attribute__((ext_vector_type(4)))  float f32x4;

__device__ __forceinline__ short f2bf(float f) {
    __hip_bfloat16 b = __float2bfloat16(f);
    unsigned short u;
    __builtin_memcpy(&u, &b, 2);
    return (short)u;
}
__device__ __forceinline__ float bf2f(short s) {
    return __uint_as_float(((unsigned)(unsigned short)s) << 16);
}
__device__ __forceinline__ f32x16 zero16() {
    f32x16 z;
#pragma unroll
    for (int i = 0; i < 16; ++i) z[i] = 0.f;
    return z;
}

// Pre-fragment weight W [K x ncols] (f32 row-major) into MFMA B-frags in LDS.
// Frag (ct, ks): cols [32ct,32ct+32), k [16ks,16ks+16).
// Lane l, elem j:  k = 16ks + 8*(l>>5) + j, col = 32ct + (l&31).
// Same contiguous k-map is used for every A operand -> consistent pairing.
__device__ __forceinline__ void build_frags(const float* __restrict__ W, int ncols,
                                            int nks, int nct, bf16x8* dst,
                                            int tid, int nthr) {
    int total = nct * nks * 64;
    for (int p = tid; p < total; p += nthr) {
        int fi = p >> 6, l = p & 63;
        int ct = fi / nks, ks = fi - ct * nks;
        int col = 32 * ct + (l & 31);
        int kb  = 16 * ks + 8 * (l >> 5);
        bf16x8 v;
#pragma unroll
        for (int j = 0; j < 8; ++j) v[j] = f2bf(W[(size_t)(kb + j) * ncols + col]);
        dst[p] = v;
    }
}

// -------- node precompute: M1[n] = relu(h[n]@Wn1 + b)@Wn2  (bf16 out), out = h --------
__global__ __launch_bounds__(512, 2) void node_kernel(
        const float* __restrict__ h, const float* __restrict__ Wn1,
        const float* __restrict__ bn1, const float* __restrict__ Wn2,
        unsigned short* __restrict__ M1, float* __restrict__ out, int ntiles) {
    __shared__ bf16x8 fWn1[16 * 64];
    __shared__ bf16x8 fWn2[32 * 64];
    __shared__ float  bias[HD];
    __shared__ __align__(16) char stg[8][8192];

    int tid = threadIdx.x;
    build_frags(Wn1, HD, 4, 4, fWn1, tid, 512);
    build_frags(Wn2, HD, 8, 4, fWn2, tid, 512);
    if (tid < HD) bias[tid] = bn1[tid];
    __syncthreads();

    int wv = tid >> 6, lane = tid & 63;
    int la = lane & 31, hh = lane >> 5;
    char* stage = stg[wv];

    float bv[4];
#pragma unroll
    for (int ct = 0; ct < 4; ++ct) bv[ct] = bias[32 * ct + la];

    int tile = blockIdx.x * 8 + wv;
    if (tile >= ntiles) return;
    int n0 = tile * 32;
    int nd = n0 + la;
    int ndc = nd < NN ? nd : NN - 1;

    // stage 1: T = relu(h @ Wn1 + b); also out = h
    f32x16 accT[4] = {zero16(), zero16(), zero16(), zero16()};
#pragma unroll
    for (int ks = 0; ks < 4; ++ks) {
        int cb = 16 * ks + 8 * hh;
        f32x4 h0 = *(const f32x4*)&h[(size_t)ndc * DNODE + cb];
        f32x4 h1 = *(const f32x4*)&h[(size_t)ndc * DNODE + cb + 4];
        if (nd < NN) {
            *(f32x4*)&out[(size_t)nd * DNODE + cb]     = h0;
            *(f32x4*)&out[(size_t)nd * DNODE + cb + 4] = h1;
        }
        bf16x8 a;
#pragma unroll
        for (int j = 0; j < 4; ++j) { a[j] = f2bf(h0[j]); a[4 + j] = f2bf(h1[j]); }
#pragma unroll
        for (int ct = 0; ct < 4; ++ct)
            accT[ct] = __builtin_amdgcn_mfma_f32_32x32x16_bf16(a, fWn1[(ct * 4 + ks) * 64 + lane], accT[ct], 0, 0, 0);
    }
    // epilogue -> swizzled staging [32][128] bf16 (row bytes 256)
#pragma unroll
    for (int ct = 0; ct < 4; ++ct)
#pragma unroll
        for (int r = 0; r < 16; ++r) {
            int row = (r & 3) + 8 * (r >> 2) + 4 * hh;
            float v = fmaxf(accT[ct][r] + bv[ct], 0.f);
            int col = 32 * ct + la;
            *(short*)&stage[row * 256 + ((2 * col) ^ ((row & 7) << 4))] = f2bf(v);
        }
    // stage 2: M1 = T @ Wn2
    f32x16 accM[4] = {zero16(), zero16(), zero16(), zero16()};
#pragma unroll
    for (int ks = 0; ks < 8; ++ks) {
        int k0 = 16 * ks + 8 * hh;
        bf16x8 a = *(const bf16x8*)&stage[la * 256 + ((2 * k0) ^ ((la & 7) << 4))];
#pragma unroll
        for (int ct = 0; ct < 4; ++ct)
            accM[ct] = __builtin_amdgcn_mfma_f32_32x32x16_bf16(a, fWn2[(ct * 8 + ks) * 64 + lane], accM[ct], 0, 0, 0);
    }
#pragma unroll
    for (int ct = 0; ct < 4; ++ct)
#pragma unroll
        for (int r = 0; r < 16; ++r) {
            int row = (r & 3) + 8 * (r >> 2) + 4 * hh;
            int node = n0 + row;
            if (node < NN)
                M1[(size_t)node * HD + 32 * ct + la] = (unsigned short)f2bf(accM[ct][r]);
        }
}

// -------- edge kernel: full per-edge chain, 32 edges per wave-tile --------
__global__ __launch_bounds__(512, 2) void edge_kernel(
        const float* __restrict__ h, const float* __restrict__ eh,
        const float* __restrict__ Wue, const float* __restrict__ We1,
        const float* __restrict__ be1, const float* __restrict__ We2,
        const float* __restrict__ Wcb, const int* __restrict__ src,
        const int* __restrict__ dst, const unsigned short* __restrict__ M1,
        float* __restrict__ out) {
    __shared__ bf16x8 fUe[8 * 64];     //  8 KB : W_ue   [64x64]
    __shared__ bf16x8 fE1[16 * 64];    // 16 KB : W_e1   [64x128]
    __shared__ bf16x8 fE2[32 * 64];    // 32 KB : W_e2   [128x128]
    __shared__ bf16x8 fCb[16 * 64];    // 16 KB : W_comb [128x64]
    __shared__ float  bias[HD];
    __shared__ __align__(16) char stg[8][8192];  // per-wave staging
    __shared__ int    sdd[8][32];

    int tid = threadIdx.x;
    build_frags(Wue, 64, 4, 2, fUe, tid, 512);
    build_frags(We1, HD, 4, 4, fE1, tid, 512);
    build_frags(We2, HD, 8, 4, fE2, tid, 512);
    build_frags(Wcb, 64, 8, 2, fCb, tid, 512);
    if (tid < HD) bias[tid] = be1[tid];
    __syncthreads();

    int wv = tid >> 6, lane = tid & 63;
    int la = lane & 31, hh = lane >> 5;
    char* stage = stg[wv];

    float bv[4];
#pragma unroll
    for (int ct = 0; ct < 4; ++ct) bv[ct] = bias[32 * ct + la];

    const int NT = NE / 32;                 // 25000 tiles
    int gw = blockIdx.x * 8 + wv;           // 0..2047
    int t0 = (int)(((long long)gw * NT) >> 11);
    int t1 = (int)(((long long)(gw + 1) * NT) >> 11);

    for (int t = t0; t < t1; ++t) {
        int e0 = t * 32;
        if (lane < 32) sdd[wv][lane] = dst[e0 + lane];
        int srcA = src[e0 + la];
        int dstA = dst[e0 + la];

        int dstD[16];
#pragma unroll
        for (int r = 0; r < 16; ++r)
            dstD[r] = sdd[wv][(r & 3) + 8 * (r >> 2) + 4 * hh];

        // prefetch eh at C/D positions
        float ehv[2][16];
#pragma unroll
        for (int ct = 0; ct < 2; ++ct)
#pragma unroll
            for (int r = 0; r < 16; ++r) {
                int row = (r & 3) + 8 * (r >> 2) + 4 * hh;
                ehv[ct][r] = eh[(size_t)(e0 + row) * 64 + 32 * ct + la];
            }

        // gather M1[src] in A-frag layout (16B contiguous per lane)
        bf16x8 mv[8];
#pragma unroll
        for (int ks = 0; ks < 8; ++ks)
            mv[ks] = *(const bf16x8*)((const char*)M1 + (size_t)srcA * 256 + 32 * ks + 16 * hh);

        // stage U: (hs .* hd) @ W_ue
        f32x16 accU[2] = {zero16(), zero16()};
#pragma unroll
        for (int ks = 0; ks < 4; ++ks) {
            int cb = 16 * ks + 8 * hh;
            f32x4 s0 = *(const f32x4*)&h[(size_t)srcA * 64 + cb];
            f32x4 s1 = *(const f32x4*)&h[(size_t)srcA * 64 + cb + 4];
            f32x4 d0 = *(const f32x4*)&h[(size_t)dstA * 64 + cb];
            f32x4 d1 = *(const f32x4*)&h[(size_t)dstA * 64 + cb + 4];
            bf16x8 a;
#pragma unroll
            for (int j = 0; j < 4; ++j) {
                a[j]     = f2bf(s0[j] * d0[j]);
                a[4 + j] = f2bf(s1[j] * d1[j]);
            }
#pragma unroll
            for (int ct = 0; ct < 2; ++ct)
                accU[ct] = __builtin_amdgcn_mfma_f32_32x32x16_bf16(a, fUe[(ct * 4 + ks) * 64 + lane], accU[ct], 0, 0, 0);
        }
        // epilogue U: ehn = 0.8 eh + 0.2 U -> staging (row bytes 128)
#pragma unroll
        for (int ct = 0; ct < 2; ++ct)
#pragma unroll
            for (int r = 0; r < 16; ++r) {
                int row = (r & 3) + 8 * (r >> 2) + 4 * hh;
                float v = 0.8f * ehv[ct][r] + 0.2f * accU[ct][r];
                int col = 32 * ct + la;
                *(short*)&stage[row * 128 + ((2 * col) ^ ((row & 7) << 4))] = f2bf(v);
            }
        // stage T2: relu(ehn @ We1 + b)
        f32x16 accT[4] = {zero16(), zero16(), zero16(), zero16()};
#pragma unroll
        for (int ks = 0; ks < 4; ++ks) {
            int k0 = 16 * ks + 8 * hh;
            bf16x8 a = *(const bf16x8*)&stage[la * 128 + ((2 * k0) ^ ((la & 7) << 4))];
#pragma unroll
            for (int ct = 0; ct < 4; ++ct)
                accT[ct] = __builtin_amdgcn_mfma_f32_32x32x16_bf16(a, fE1[(ct * 4 + ks) * 64 + lane], accT[ct], 0, 0, 0);
        }
#pragma unroll
        for (int ct = 0; ct < 4; ++ct)
#pragma unroll
            for (int r = 0; r < 16; ++r) {
                int row = (r & 3) + 8 * (r >> 2) + 4 * hh;
                float v = fmaxf(accT[ct][r] + bv[ct], 0.f);
                int col = 32 * ct + la;
                *(short*)&stage[row * 256 + ((2 * col) ^ ((row & 7) << 4))] = f2bf(v);
            }
        // stage M2: T2 @ We2
        f32x16 accM[4] = {zero16(), zero16(), zero16(), zero16()};
#pragma unroll
        for (int ks = 0; ks < 8; ++ks) {
            int k0 = 16 * ks + 8 * hh;
            bf16x8 a = *(const bf16x8*)&stage[la * 256 + ((2 * k0) ^ ((la & 7) << 4))];
#pragma unroll
            for (int ct = 0; ct < 4; ++ct)
                accM[ct] = __builtin_amdgcn_mfma_f32_32x32x16_bf16(a, fE2[(ct * 8 + ks) * 64 + lane], accM[ct], 0, 0, 0);
        }
#pragma unroll
        for (int ct = 0; ct < 4; ++ct)
#pragma unroll
            for (int r = 0; r < 16; ++r) {
                int row = (r & 3) + 8 * (r >> 2) + 4 * hh;
                int col = 32 * ct + la;
                *(short*)&stage[row * 256 + ((2 * col) ^ ((row & 7) << 4))] = f2bf(accM[ct][r]);
            }
        // stage F: P = M1 .* M2 ; m = tanh(P @ Wcb) ; scatter
        f32x16 accF[2] = {zero16(), zero16()};
#pragma unroll
        for (int ks = 0; ks < 8; ++ks) {
            int k0 = 16 * ks + 8 * hh;
            bf16x8 m2 = *(const bf16x8*)&stage[la * 256 + ((2 * k0) ^ ((la & 7) << 4))];
            bf16x8 ap;
#pragma unroll
            for (int i = 0; i < 8; ++i)
                ap[i] = f2bf(bf2f(m2[i]) * bf2f(mv[ks][i]));
#pragma unroll
            for (int ct = 0; ct < 2; ++ct)
                accF[ct] = __builtin_amdgcn_mfma_f32_32x32x16_bf16(ap, fCb[(ct * 8 + ks) * 64 + lane], accF[ct], 0, 0, 0);
        }
#pragma unroll
        for (int ct = 0; ct < 2; ++ct)
#pragma unroll
            for (int r = 0; r < 16; ++r) {
                float x = accF[ct][r];
                x = fminf(fmaxf(x, -10.f), 10.f);
                float ex = __expf(2.f * x);
                float m = (ex - 1.f) * __builtin_amdgcn_rcpf(ex + 1.f);
                unsafeAtomicAdd(&out[(size_t)dstD[r] * 64 + 32 * ct + la], m);
            }
    }
}

extern "C" void kernel_launch(void* const* d_in, const int* in_sizes, int n_in,
                              void* d_out, int out_size, void* d_ws, size_t ws_size,
                              hipStream_t stream) {
    const float* h   = (const float*)d_in[0];
    const float* eh  = (const float*)d_in[1];
    const float* Wn1 = (const float*)d_in[2];
    const float* bn1 = (const float*)d_in[3];
    const float* Wn2 = (const float*)d_in[4];
    const float* We1 = (const float*)d_in[5];
    const float* be1 = (const float*)d_in[6];
    const float* We2 = (const float*)d_in[7];
    const float* Wcb = (const float*)d_in[8];
    const float* Wue = (const float*)d_in[9];
    const int*   src = (const int*)d_in[10];
    const int*   dst = (const int*)d_in[11];
    float* out = (float*)d_out;
    unsigned short* M1 = (unsigned short*)d_ws;  // NN*HD bf16 = 12.8 MB scratch

    int ntiles = (NN + 31) / 32;  // 1563
    node_kernel<<<(ntiles + 7) / 8, 512, 0, stream>>>(h, Wn1, bn1, Wn2, M1, out, ntiles);
    edge_kernel<<<256, 512, 0, stream>>>(h, eh, Wue, We1, be1, We2, Wcb, src, dst, M1, out);
}

// Round 3
// 519.150 us; speedup vs baseline: 1.0084x; 1.0084x over previous
//
#include <hip/hip_runtime.h>
#include <hip/hip_bf16.h>

#define NN 50000
#define NE 800000
#define DNODE 64
#define HD 128

typedef __attribute__((ext_vector_type(8)))  short bf16x8;   // 8 bf16 (4 VGPRs)
typedef __attribute__((ext_vector_type(16))) float f32x16;   // MFMA C/D
typedef __attribute__((ext_vector_type(4)))  float f32x4;
typedef __attribute__((ext_vector_type(4)))  unsigned short u16x4;

__device__ __forceinline__ short f2bf(float f) {
    __hip_bfloat16 b = __float2bfloat16(f);
    unsigned short u;
    __builtin_memcpy(&u, &b, 2);
    return (short)u;
}
__device__ __forceinline__ float bf2f(unsigned short s) {
    return __uint_as_float(((unsigned)s) << 16);
}
__device__ __forceinline__ f32x16 zero16() {
    f32x16 z;
#pragma unroll
    for (int i = 0; i < 16; ++i) z[i] = 0.f;
    return z;
}

__device__ __forceinline__ unsigned cvt_pk(float lo, float hi) {
    unsigned r;
    asm("v_cvt_pk_bf16_f32 %0, %1, %2" : "=v"(r) : "v"(lo), "v"(hi));
    return r;
}

// Convert 16 f32 C/D-domain values of one ct (vals[4m+j] = Y[local feat
// 8m+4hh+j, col la]) into B/A-frags. Frag word derivation (low frag, 2ct):
//   word0 = (hh0: own m0-lo  | hh1: partner m1-lo)
//   word2 = (hh0: partner m0-lo | hh1: own m1-lo)
// v_permlane32_swap_b32 semantics: DST.row1 <-> SRC.row0. So
// swap(dst=m0_word, src=m1_word) yields dst=word0, src=word2 directly.
__device__ __forceinline__ bf16x8 pack_swap(const float* v) {
    unsigned w0 = cvt_pk(v[0], v[1]);   // own m=0 lo pair
    unsigned w1 = cvt_pk(v[2], v[3]);   // own m=0 hi pair
    unsigned w2 = cvt_pk(v[4], v[5]);   // own m=1 lo pair
    unsigned w3 = cvt_pk(v[6], v[7]);   // own m=1 hi pair
    asm("v_permlane32_swap_b32 %0, %1" : "+v"(w0), "+v"(w2));
    asm("v_permlane32_swap_b32 %0, %1" : "+v"(w1), "+v"(w3));
    union { unsigned u[4]; bf16x8 f; } o;
    o.u[0] = w0; o.u[1] = w1; o.u[2] = w2; o.u[3] = w3;
    return o.f;
}

// Pre-fragment weight W [K x ncols] (f32 row-major) into MFMA frags in LDS.
// Frag (ct, ks): lane l, elem j:  k = 16ks + 8*(l>>5) + j, col = 32ct + (l&31).
// Used as A operand (swapped stages) or B operand (normal stages) — the lane
// map is identical for both; pairing consistency verified in round 1.
__device__ __forceinline__ void build_frags(const float* __restrict__ W, int ncols,
                                            int nks, int nct, bf16x8* dst,
                                            int tid, int nthr) {
    int total = nct * nks * 64;
    for (int p = tid; p < total; p += nthr) {
        int fi = p >> 6, l = p & 63;
        int ct = fi / nks, ks = fi - ct * nks;
        int col = 32 * ct + (l & 31);
        int kb  = 16 * ks + 8 * (l >> 5);
        bf16x8 v;
#pragma unroll
        for (int j = 0; j < 8; ++j) v[j] = f2bf(W[(size_t)(kb + j) * ncols + col]);
        dst[p] = v;
    }
}

// -------- node precompute: M1[n] = relu(h[n]@Wn1 + b)@Wn2  (bf16 out), out = h --------
__global__ __launch_bounds__(512, 4) void node_kernel(
        const float* __restrict__ h, const float* __restrict__ Wn1,
        const float* __restrict__ bn1, const float* __restrict__ Wn2,
        unsigned short* __restrict__ M1, float* __restrict__ out, int ntiles) {
    __shared__ bf16x8 fWn1[16 * 64];   // 16 KB
    __shared__ bf16x8 fWn2[32 * 64];   // 32 KB
    __shared__ float  bias[HD];

    int tid = threadIdx.x;
    build_frags(Wn1, HD, 4, 4, fWn1, tid, 512);
    build_frags(Wn2, HD, 8, 4, fWn2, tid, 512);
    if (tid < HD) bias[tid] = bn1[tid];
    __syncthreads();

    int wv = tid >> 6, lane = tid & 63;
    int la = lane & 31, hh = lane >> 5;

    int tile = blockIdx.x * 8 + wv;
    if (tile >= ntiles) return;
    int n0 = tile * 32;
    int n_la = n0 + la;
    int nc = n_la < NN ? n_la : NN - 1;

    // h frags (B operand, swapped stage 1) + out = h copy
    bf16x8 hfrag[4];
#pragma unroll
    for (int ks = 0; ks < 4; ++ks) {
        int cb = 16 * ks + 8 * hh;
        f32x4 h0 = *(const f32x4*)&h[(size_t)nc * DNODE + cb];
        f32x4 h1 = *(const f32x4*)&h[(size_t)nc * DNODE + cb + 4];
        if (n_la < NN) {
            *(f32x4*)&out[(size_t)n_la * DNODE + cb]     = h0;
            *(f32x4*)&out[(size_t)n_la * DNODE + cb + 4] = h1;
        }
        union { unsigned u[4]; bf16x8 f; } xf;
        xf.u[0] = cvt_pk(h0[0], h0[1]);
        xf.u[1] = cvt_pk(h0[2], h0[3]);
        xf.u[2] = cvt_pk(h1[0], h1[1]);
        xf.u[3] = cvt_pk(h1[2], h1[3]);
        hfrag[ks] = xf.f;
    }

    // stage 1 (swapped): T^T[f, n] = Wn1^T . X^T ; bias+relu ; pack -> tfrag
    bf16x8 tfrag[8];
#pragma unroll
    for (int ct = 0; ct < 4; ++ct) {
        f32x16 acc = zero16();
#pragma unroll
        for (int ks = 0; ks < 4; ++ks)
            acc = __builtin_amdgcn_mfma_f32_32x32x16_bf16(fWn1[(ct * 4 + ks) * 64 + lane], hfrag[ks], acc, 0, 0, 0);
        float vals[16];
#pragma unroll
        for (int m = 0; m < 4; ++m) {
            f32x4 bv = *(const f32x4*)&bias[32 * ct + 8 * m + 4 * hh];
#pragma unroll
            for (int j = 0; j < 4; ++j)
                vals[4 * m + j] = fmaxf(acc[4 * m + j] + bv[j], 0.f);
        }
        tfrag[2 * ct]     = pack_swap(&vals[0]);
        tfrag[2 * ct + 1] = pack_swap(&vals[8]);
    }

    // stage 2 (normal): M1 = T @ Wn2 ; store bf16 rows
#pragma unroll
    for (int ct = 0; ct < 4; ++ct) {
        f32x16 acc = zero16();
#pragma unroll
        for (int ks = 0; ks < 8; ++ks)
            acc = __builtin_amdgcn_mfma_f32_32x32x16_bf16(tfrag[ks], fWn2[(ct * 8 + ks) * 64 + lane], acc, 0, 0, 0);
#pragma unroll
        for (int r = 0; r < 16; ++r) {
            int row = (r & 3) + 8 * (r >> 2) + 4 * hh;
            int node = n0 + row;
            if (node < NN)
                M1[(size_t)node * HD + 32 * ct + la] = (unsigned short)f2bf(acc[r]);
        }
    }
}

// -------- edge kernel: full per-edge chain, 32 edges per wave-tile, no staging LDS --------
__global__ __launch_bounds__(512, 4) void edge_kernel(
        const float* __restrict__ h, const float* __restrict__ eh,
        const float* __restrict__ Wue, const float* __restrict__ We1,
        const float* __restrict__ be1, const float* __restrict__ We2,
        const float* __restrict__ Wcb, const int* __restrict__ src,
        const int* __restrict__ dst, const unsigned short* __restrict__ M1,
        float* __restrict__ out) {
    __shared__ bf16x8 fUe[8 * 64];     //  8 KB : W_ue   [64x64]
    __shared__ bf16x8 fE1[16 * 64];    // 16 KB : W_e1   [64x128]
    __shared__ bf16x8 fE2[32 * 64];    // 32 KB : W_e2   [128x128]
    __shared__ bf16x8 fCb[16 * 64];    // 16 KB : W_comb [128x64]
    __shared__ float  bias[HD];        // total 72.5 KB -> 2 blocks/CU

    int tid = threadIdx.x;
    build_frags(Wue, 64, 4, 2, fUe, tid, 512);
    build_frags(We1, HD, 4, 4, fE1, tid, 512);
    build_frags(We2, HD, 8, 4, fE2, tid, 512);
    build_frags(Wcb, 64, 8, 2, fCb, tid, 512);
    if (tid < HD) bias[tid] = be1[tid];
    __syncthreads();

    int wv = tid >> 6, lane = tid & 63;
    int la = lane & 31, hh = lane >> 5;

    const int NT = NE / 32;                 // 25000 tiles
    int gw = blockIdx.x * 8 + wv;           // 0..4095
    int t0 = (int)(((long long)gw * NT) >> 12);
    int t1 = (int)(((long long)(gw + 1) * NT) >> 12);

    for (int t = t0; t < t1; ++t) {
        int e0 = t * 32;
        int e_la = e0 + la;
        int srcA = src[e_la];
        int dstA = dst[e_la];

        // ---- stage U (swapped): U^T[f, e] = Wue^T . (hs.*hd)^T ----
        f32x16 accU0 = zero16(), accU1 = zero16();
#pragma unroll
        for (int ks = 0; ks < 4; ++ks) {
            int cb = 16 * ks + 8 * hh;
            f32x4 s0 = *(const f32x4*)&h[(size_t)srcA * DNODE + cb];
            f32x4 s1 = *(const f32x4*)&h[(size_t)srcA * DNODE + cb + 4];
            f32x4 d0 = *(const f32x4*)&h[(size_t)dstA * DNODE + cb];
            f32x4 d1 = *(const f32x4*)&h[(size_t)dstA * DNODE + cb + 4];
            union { unsigned u[4]; bf16x8 f; } xf;
            xf.u[0] = cvt_pk(s0[0] * d0[0], s0[1] * d0[1]);
            xf.u[1] = cvt_pk(s0[2] * d0[2], s0[3] * d0[3]);
            xf.u[2] = cvt_pk(s1[0] * d1[0], s1[1] * d1[1]);
            xf.u[3] = cvt_pk(s1[2] * d1[2], s1[3] * d1[3]);
            accU0 = __builtin_amdgcn_mfma_f32_32x32x16_bf16(fUe[(0 * 4 + ks) * 64 + lane], xf.f, accU0, 0, 0, 0);
            accU1 = __builtin_amdgcn_mfma_f32_32x32x16_bf16(fUe[(1 * 4 + ks) * 64 + lane], xf.f, accU1, 0, 0, 0);
        }

        // ---- U epilogue: ehn = 0.8 eh + 0.2 U ; pack -> efrag ----
        bf16x8 efrag[4];
#pragma unroll
        for (int ct = 0; ct < 2; ++ct) {
            const f32x16& aU = ct ? accU1 : accU0;
            float vals[16];
#pragma unroll
            for (int m = 0; m < 4; ++m) {
                f32x4 ev = *(const f32x4*)&eh[(size_t)e_la * 64 + 32 * ct + 8 * m + 4 * hh];
#pragma unroll
                for (int j = 0; j < 4; ++j)
                    vals[4 * m + j] = 0.8f * ev[j] + 0.2f * aU[4 * m + j];
            }
            efrag[2 * ct]     = pack_swap(&vals[0]);
            efrag[2 * ct + 1] = pack_swap(&vals[8]);
        }

        // ---- stage T2 (swapped): relu(ehn @ We1 + b) -> tfrag ----
        bf16x8 tfrag[8];
#pragma unroll
        for (int ct = 0; ct < 4; ++ct) {
            f32x16 acc = zero16();
#pragma unroll
            for (int ks = 0; ks < 4; ++ks)
                acc = __builtin_amdgcn_mfma_f32_32x32x16_bf16(fE1[(ct * 4 + ks) * 64 + lane], efrag[ks], acc, 0, 0, 0);
            float vals[16];
#pragma unroll
            for (int m = 0; m < 4; ++m) {
                f32x4 bv = *(const f32x4*)&bias[32 * ct + 8 * m + 4 * hh];
#pragma unroll
                for (int j = 0; j < 4; ++j)
                    vals[4 * m + j] = fmaxf(acc[4 * m + j] + bv[j], 0.f);
            }
            tfrag[2 * ct]     = pack_swap(&vals[0]);
            tfrag[2 * ct + 1] = pack_swap(&vals[8]);
        }

        // ---- stage M2 (swapped): M2 = T2 @ We2 ; P = M1 .* M2 ; pack -> pfrag ----
        bf16x8 pfrag[8];
#pragma unroll
        for (int ct = 0; ct < 4; ++ct) {
            u16x4 mq[4];
#pragma unroll
            for (int m = 0; m < 4; ++m)
                mq[m] = *(const u16x4*)&M1[(size_t)srcA * HD + 32 * ct + 8 * m + 4 * hh];
            f32x16 acc = zero16();
#pragma unroll
            for (int ks = 0; ks < 8; ++ks)
                acc = __builtin_amdgcn_mfma_f32_32x32x16_bf16(fE2[(ct * 8 + ks) * 64 + lane], tfrag[ks], acc, 0, 0, 0);
            float vals[16];
#pragma unroll
            for (int m = 0; m < 4; ++m)
#pragma unroll
                for (int j = 0; j < 4; ++j)
                    vals[4 * m + j] = acc[4 * m + j] * bf2f(mq[m][j]);
            pfrag[2 * ct]     = pack_swap(&vals[0]);
            pfrag[2 * ct + 1] = pack_swap(&vals[8]);
        }

        // dst broadcast for scatter rows (C/D row r maps to tile row below)
        int dstR[16];
#pragma unroll
        for (int r = 0; r < 16; ++r)
            dstR[r] = __shfl(dstA, (r & 3) + 8 * (r >> 2) + 4 * hh);

        // ---- stage F (normal): m = tanh(P @ Wcb) ; coalesced atomic scatter ----
#pragma unroll
        for (int ct = 0; ct < 2; ++ct) {
            f32x16 acc = zero16();
#pragma unroll
            for (int ks = 0; ks < 8; ++ks)
                acc = __builtin_amdgcn_mfma_f32_32x32x16_bf16(pfrag[ks], fCb[(ct * 8 + ks) * 64 + lane], acc, 0, 0, 0);
#pragma unroll
            for (int r = 0; r < 16; ++r) {
                float x = acc[r];
                x = fminf(fmaxf(x, -10.f), 10.f);
                float ex = __expf(2.f * x);
                float m = (ex - 1.f) * __builtin_amdgcn_rcpf(ex + 1.f);
                unsafeAtomicAdd(&out[(size_t)dstR[r] * DNODE + 32 * ct + la], m);
            }
        }
    }
}

extern "C" void kernel_launch(void* const* d_in, const int* in_sizes, int n_in,
                              void* d_out, int out_size, void* d_ws, size_t ws_size,
                              hipStream_t stream) {
    const float* h   = (const float*)d_in[0];
    const float* eh  = (const float*)d_in[1];
    const float* Wn1 = (const float*)d_in[2];
    const float* bn1 = (const float*)d_in[3];
    const float* Wn2 = (const float*)d_in[4];
    const float* We1 = (const float*)d_in[5];
    const float* be1 = (const float*)d_in[6];
    const float* We2 = (const float*)d_in[7];
    const float* Wcb = (const float*)d_in[8];
    const float* Wue = (const float*)d_in[9];
    const int*   src = (const int*)d_in[10];
    const int*   dst = (const int*)d_in[11];
    float* out = (float*)d_out;
    unsigned short* M1 = (unsigned short*)d_ws;  // NN*HD bf16 = 12.8 MB scratch

    int ntiles = (NN + 31) / 32;  // 1563
    node_kernel<<<(ntiles + 7) / 8, 512, 0, stream>>>(h, Wn1, bn1, Wn2, M1, out, ntiles);
    edge_kernel<<<512, 512, 0, stream>>>(h, eh, Wue, We1, be1, We2, Wcb, src, dst, M1, out);
}

// Round 4
// 478.038 us; speedup vs baseline: 1.0951x; 1.0860x over previous
//
#include <hip/hip_runtime.h>
#include <hip/hip_bf16.h>

#define NN 50000
#define NE 800000
#define DNODE 64
#define HD 128

typedef __attribute__((ext_vector_type(8)))  short bf16x8;   // 8 bf16 (4 VGPRs)
typedef __attribute__((ext_vector_type(16))) float f32x16;   // MFMA C/D
typedef __attribute__((ext_vector_type(4)))  float f32x4;
typedef __attribute__((ext_vector_type(4)))  unsigned short u16x4;
typedef __attribute__((ext_vector_type(8)))  unsigned short u16x8;

__device__ __forceinline__ short f2bf(float f) {
    __hip_bfloat16 b = __float2bfloat16(f);
    unsigned short u;
    __builtin_memcpy(&u, &b, 2);
    return (short)u;
}
__device__ __forceinline__ float bf2f(unsigned short s) {
    return __uint_as_float(((unsigned)s) << 16);
}
__device__ __forceinline__ f32x16 zero16() {
    f32x16 z;
#pragma unroll
    for (int i = 0; i < 16; ++i) z[i] = 0.f;
    return z;
}

__device__ __forceinline__ unsigned cvt_pk(float lo, float hi) {
    unsigned r;
    asm("v_cvt_pk_bf16_f32 %0, %1, %2" : "=v"(r) : "v"(lo), "v"(hi));
    return r;
}

// HW packed bf16 atomic add: mem[addr] += lo16, mem[addr+2] += hi16 (bf16 adds).
__device__ __forceinline__ void atomic_pk_bf16(unsigned short* addr, unsigned data) {
    unsigned long long a = (unsigned long long)(uintptr_t)addr;
    asm volatile("global_atomic_pk_add_bf16 %0, %1, off" :: "v"(a), "v"(data) : "memory");
}

// Convert 16 f32 C/D-domain values of one ct (vals[4m+j] = Y[local feat
// 8m+4hh+j, col la]) into B/A-frags. v_permlane32_swap_b32: DST.row1 <-> SRC.row0;
// swap(dst=m0_word, src=m1_word) yields dst=word0, src=word2. (verified r3)
__device__ __forceinline__ bf16x8 pack_swap(const float* v) {
    unsigned w0 = cvt_pk(v[0], v[1]);
    unsigned w1 = cvt_pk(v[2], v[3]);
    unsigned w2 = cvt_pk(v[4], v[5]);
    unsigned w3 = cvt_pk(v[6], v[7]);
    asm("v_permlane32_swap_b32 %0, %1" : "+v"(w0), "+v"(w2));
    asm("v_permlane32_swap_b32 %0, %1" : "+v"(w1), "+v"(w3));
    union { unsigned u[4]; bf16x8 f; } o;
    o.u[0] = w0; o.u[1] = w1; o.u[2] = w2; o.u[3] = w3;
    return o.f;
}

// Pre-fragment weight W [K x ncols] (f32 row-major) into MFMA frags in LDS.
// Frag (ct, ks): lane l, elem j:  k = 16ks + 8*(l>>5) + j, col = 32ct + (l&31).
__device__ __forceinline__ void build_frags(const float* __restrict__ W, int ncols,
                                            int nks, int nct, bf16x8* dst,
                                            int tid, int nthr) {
    int total = nct * nks * 64;
    for (int p = tid; p < total; p += nthr) {
        int fi = p >> 6, l = p & 63;
        int ct = fi / nks, ks = fi - ct * nks;
        int col = 32 * ct + (l & 31);
        int kb  = 16 * ks + 8 * (l >> 5);
        bf16x8 v;
#pragma unroll
        for (int j = 0; j < 8; ++j) v[j] = f2bf(W[(size_t)(kb + j) * ncols + col]);
        dst[p] = v;
    }
}

// -------- node precompute: M1[n] = relu(h[n]@Wn1 + b)@Wn2  (bf16 out) --------
__global__ __launch_bounds__(512, 4) void node_kernel(
        const float* __restrict__ h, const float* __restrict__ Wn1,
        const float* __restrict__ bn1, const float* __restrict__ Wn2,
        unsigned short* __restrict__ M1, int ntiles) {
    __shared__ bf16x8 fWn1[16 * 64];   // 16 KB
    __shared__ bf16x8 fWn2[32 * 64];   // 32 KB
    __shared__ float  bias[HD];

    int tid = threadIdx.x;
    build_frags(Wn1, HD, 4, 4, fWn1, tid, 512);
    build_frags(Wn2, HD, 8, 4, fWn2, tid, 512);
    if (tid < HD) bias[tid] = bn1[tid];
    __syncthreads();

    int wv = tid >> 6, lane = tid & 63;
    int la = lane & 31, hh = lane >> 5;

    int tile = blockIdx.x * 8 + wv;
    if (tile >= ntiles) return;
    int n0 = tile * 32;
    int n_la = n0 + la;
    int nc = n_la < NN ? n_la : NN - 1;

    bf16x8 hfrag[4];
#pragma unroll
    for (int ks = 0; ks < 4; ++ks) {
        int cb = 16 * ks + 8 * hh;
        f32x4 h0 = *(const f32x4*)&h[(size_t)nc * DNODE + cb];
        f32x4 h1 = *(const f32x4*)&h[(size_t)nc * DNODE + cb + 4];
        union { unsigned u[4]; bf16x8 f; } xf;
        xf.u[0] = cvt_pk(h0[0], h0[1]);
        xf.u[1] = cvt_pk(h0[2], h0[3]);
        xf.u[2] = cvt_pk(h1[0], h1[1]);
        xf.u[3] = cvt_pk(h1[2], h1[3]);
        hfrag[ks] = xf.f;
    }

    // stage 1 (swapped): T^T = Wn1^T . X^T ; bias+relu ; pack -> tfrag
    bf16x8 tfrag[8];
#pragma unroll
    for (int ct = 0; ct < 4; ++ct) {
        f32x16 acc = zero16();
#pragma unroll
        for (int ks = 0; ks < 4; ++ks)
            acc = __builtin_amdgcn_mfma_f32_32x32x16_bf16(fWn1[(ct * 4 + ks) * 64 + lane], hfrag[ks], acc, 0, 0, 0);
        float vals[16];
#pragma unroll
        for (int m = 0; m < 4; ++m) {
            f32x4 bv = *(const f32x4*)&bias[32 * ct + 8 * m + 4 * hh];
#pragma unroll
            for (int j = 0; j < 4; ++j)
                vals[4 * m + j] = fmaxf(acc[4 * m + j] + bv[j], 0.f);
        }
        tfrag[2 * ct]     = pack_swap(&vals[0]);
        tfrag[2 * ct + 1] = pack_swap(&vals[8]);
    }

    // stage 2 (normal): M1 = T @ Wn2
#pragma unroll
    for (int ct = 0; ct < 4; ++ct) {
        f32x16 acc = zero16();
#pragma unroll
        for (int ks = 0; ks < 8; ++ks)
            acc = __builtin_amdgcn_mfma_f32_32x32x16_bf16(tfrag[ks], fWn2[(ct * 8 + ks) * 64 + lane], acc, 0, 0, 0);
#pragma unroll
        for (int r = 0; r < 16; ++r) {
            int row = (r & 3) + 8 * (r >> 2) + 4 * hh;
            int node = n0 + row;
            if (node < NN)
                M1[(size_t)node * HD + 32 * ct + la] = (unsigned short)f2bf(acc[r]);
        }
    }
}

// -------- edge kernel: per-edge chain, 32 edges/wave-tile, bf16 pk-atomic scatter --------
__global__ __launch_bounds__(512, 4) void edge_kernel(
        const float* __restrict__ h, const float* __restrict__ eh,
        const float* __restrict__ Wue, const float* __restrict__ We1,
        const float* __restrict__ be1, const float* __restrict__ We2,
        const float* __restrict__ Wcb, const int* __restrict__ src,
        const int* __restrict__ dst, const unsigned short* __restrict__ M1,
        unsigned short* __restrict__ Macc) {
    __shared__ bf16x8 fUe[8 * 64];
    __shared__ bf16x8 fE1[16 * 64];
    __shared__ bf16x8 fE2[32 * 64];
    __shared__ bf16x8 fCb[16 * 64];
    __shared__ float  bias[HD];        // 72.5 KB -> 2 blocks/CU

    int tid = threadIdx.x;
    build_frags(Wue, 64, 4, 2, fUe, tid, 512);
    build_frags(We1, HD, 4, 4, fE1, tid, 512);
    build_frags(We2, HD, 8, 4, fE2, tid, 512);
    build_frags(Wcb, 64, 8, 2, fCb, tid, 512);
    if (tid < HD) bias[tid] = be1[tid];
    __syncthreads();

    int wv = tid >> 6, lane = tid & 63;
    int la = lane & 31, hh = lane >> 5;

    const int NT = NE / 32;
    int gw = blockIdx.x * 8 + wv;           // 0..4095
    int t0 = (int)(((long long)gw * NT) >> 12);
    int t1 = (int)(((long long)(gw + 1) * NT) >> 12);
    if (t0 >= t1) return;

    int srcA = src[t0 * 32 + la];
    int dstA = dst[t0 * 32 + la];

    for (int t = t0; t < t1; ++t) {
        int e_la = t * 32 + la;
        // prefetch next tile's indices
        int eN = (t + 1 < t1) ? (t + 1) * 32 + la : e_la;
        int srcN = src[eN];
        int dstN = dst[eN];

        // ---- hoisted long-latency loads: M1[src] frags + eh row ----
        u16x4 mq[16];
#pragma unroll
        for (int ct = 0; ct < 4; ++ct)
#pragma unroll
            for (int m = 0; m < 4; ++m)
                mq[4 * ct + m] = *(const u16x4*)&M1[(size_t)srcA * HD + 32 * ct + 8 * m + 4 * hh];
        f32x4 ehq[8];
#pragma unroll
        for (int ct = 0; ct < 2; ++ct)
#pragma unroll
            for (int m = 0; m < 4; ++m)
                ehq[4 * ct + m] = *(const f32x4*)&eh[(size_t)e_la * 64 + 32 * ct + 8 * m + 4 * hh];

        // ---- stage U (swapped): U^T = Wue^T . (hs.*hd)^T ----
        f32x16 accU0 = zero16(), accU1 = zero16();
#pragma unroll
        for (int ks = 0; ks < 4; ++ks) {
            int cb = 16 * ks + 8 * hh;
            f32x4 s0 = *(const f32x4*)&h[(size_t)srcA * DNODE + cb];
            f32x4 s1 = *(const f32x4*)&h[(size_t)srcA * DNODE + cb + 4];
            f32x4 d0 = *(const f32x4*)&h[(size_t)dstA * DNODE + cb];
            f32x4 d1 = *(const f32x4*)&h[(size_t)dstA * DNODE + cb + 4];
            union { unsigned u[4]; bf16x8 f; } xf;
            xf.u[0] = cvt_pk(s0[0] * d0[0], s0[1] * d0[1]);
            xf.u[1] = cvt_pk(s0[2] * d0[2], s0[3] * d0[3]);
            xf.u[2] = cvt_pk(s1[0] * d1[0], s1[1] * d1[1]);
            xf.u[3] = cvt_pk(s1[2] * d1[2], s1[3] * d1[3]);
            accU0 = __builtin_amdgcn_mfma_f32_32x32x16_bf16(fUe[(0 * 4 + ks) * 64 + lane], xf.f, accU0, 0, 0, 0);
            accU1 = __builtin_amdgcn_mfma_f32_32x32x16_bf16(fUe[(1 * 4 + ks) * 64 + lane], xf.f, accU1, 0, 0, 0);
        }

        // ---- U epilogue: ehn = 0.8 eh + 0.2 U ; pack -> efrag ----
        bf16x8 efrag[4];
#pragma unroll
        for (int ct = 0; ct < 2; ++ct) {
            const f32x16& aU = ct ? accU1 : accU0;
            float vals[16];
#pragma unroll
            for (int m = 0; m < 4; ++m)
#pragma unroll
                for (int j = 0; j < 4; ++j)
                    vals[4 * m + j] = 0.8f * ehq[4 * ct + m][j] + 0.2f * aU[4 * m + j];
            efrag[2 * ct]     = pack_swap(&vals[0]);
            efrag[2 * ct + 1] = pack_swap(&vals[8]);
        }

        // ---- stage T2 (swapped): relu(ehn @ We1 + b) -> tfrag ----
        bf16x8 tfrag[8];
#pragma unroll
        for (int ct = 0; ct < 4; ++ct) {
            f32x16 acc = zero16();
#pragma unroll
            for (int ks = 0; ks < 4; ++ks)
                acc = __builtin_amdgcn_mfma_f32_32x32x16_bf16(fE1[(ct * 4 + ks) * 64 + lane], efrag[ks], acc, 0, 0, 0);
            float vals[16];
#pragma unroll
            for (int m = 0; m < 4; ++m) {
                f32x4 bv = *(const f32x4*)&bias[32 * ct + 8 * m + 4 * hh];
#pragma unroll
                for (int j = 0; j < 4; ++j)
                    vals[4 * m + j] = fmaxf(acc[4 * m + j] + bv[j], 0.f);
            }
            tfrag[2 * ct]     = pack_swap(&vals[0]);
            tfrag[2 * ct + 1] = pack_swap(&vals[8]);
        }

        // ---- stage M2 (swapped): M2 = T2 @ We2 ; P = M1 .* M2 ; pack -> pfrag ----
        bf16x8 pfrag[8];
#pragma unroll
        for (int ct = 0; ct < 4; ++ct) {
            f32x16 acc = zero16();
#pragma unroll
            for (int ks = 0; ks < 8; ++ks)
                acc = __builtin_amdgcn_mfma_f32_32x32x16_bf16(fE2[(ct * 8 + ks) * 64 + lane], tfrag[ks], acc, 0, 0, 0);
            float vals[16];
#pragma unroll
            for (int m = 0; m < 4; ++m)
#pragma unroll
                for (int j = 0; j < 4; ++j)
                    vals[4 * m + j] = acc[4 * m + j] * bf2f(mq[4 * ct + m][j]);
            pfrag[2 * ct]     = pack_swap(&vals[0]);
            pfrag[2 * ct + 1] = pack_swap(&vals[8]);
        }

        // dst rows for scatter
        int dstR[16];
#pragma unroll
        for (int r = 0; r < 16; ++r)
            dstR[r] = __shfl(dstA, (r & 3) + 8 * (r >> 2) + 4 * hh);

        // ---- stage F (normal): m = tanh(P @ Wcb) ; packed bf16 atomic scatter ----
        f32x16 accF0 = zero16(), accF1 = zero16();
#pragma unroll
        for (int ks = 0; ks < 8; ++ks) {
            accF0 = __builtin_amdgcn_mfma_f32_32x32x16_bf16(pfrag[ks], fCb[(0 * 8 + ks) * 64 + lane], accF0, 0, 0, 0);
            accF1 = __builtin_amdgcn_mfma_f32_32x32x16_bf16(pfrag[ks], fCb[(1 * 8 + ks) * 64 + lane], accF1, 0, 0, 0);
        }
        int odd = lane & 1;
#pragma unroll
        for (int r = 0; r < 16; ++r) {
            float x0 = fminf(fmaxf(accF0[r], -10.f), 10.f);
            float x1 = fminf(fmaxf(accF1[r], -10.f), 10.f);
            float ex0 = __expf(2.f * x0), ex1 = __expf(2.f * x1);
            float m0 = (ex0 - 1.f) * __builtin_amdgcn_rcpf(ex0 + 1.f);
            float m1 = (ex1 - 1.f) * __builtin_amdgcn_rcpf(ex1 + 1.f);
            float e0 = __shfl_xor(m0, 1);
            float e1 = __shfl_xor(m1, 1);
            // even lane: cols (la, la+1) of ct0; odd lane: cols (31+la, 32+la) of ct1
            unsigned w = odd ? cvt_pk(e1, m1) : cvt_pk(m0, e0);
            int colstart = odd ? (31 + la) : la;
            atomic_pk_bf16(&Macc[(size_t)dstR[r] * 64 + colstart], w);
        }

        srcA = srcN;
        dstA = dstN;
    }
}

// -------- combine: out = h + Macc (bf16 -> f32) --------
__global__ __launch_bounds__(256) void combine_kernel(
        const float* __restrict__ h, const unsigned short* __restrict__ Macc,
        float* __restrict__ out) {
    int i = (blockIdx.x * 256 + threadIdx.x) * 8;
    if (i >= NN * DNODE) return;
    u16x8 mv = *(const u16x8*)&Macc[i];
    f32x4 h0 = *(const f32x4*)&h[i];
    f32x4 h1 = *(const f32x4*)&h[i + 4];
    f32x4 o0, o1;
#pragma unroll
    for (int j = 0; j < 4; ++j) {
        o0[j] = h0[j] + bf2f(mv[j]);
        o1[j] = h1[j] + bf2f(mv[4 + j]);
    }
    *(f32x4*)&out[i]     = o0;
    *(f32x4*)&out[i + 4] = o1;
}

extern "C" void kernel_launch(void* const* d_in, const int* in_sizes, int n_in,
                              void* d_out, int out_size, void* d_ws, size_t ws_size,
                              hipStream_t stream) {
    const float* h   = (const float*)d_in[0];
    const float* eh  = (const float*)d_in[1];
    const float* Wn1 = (const float*)d_in[2];
    const float* bn1 = (const float*)d_in[3];
    const float* Wn2 = (const float*)d_in[4];
    const float* We1 = (const float*)d_in[5];
    const float* be1 = (const float*)d_in[6];
    const float* We2 = (const float*)d_in[7];
    const float* Wcb = (const float*)d_in[8];
    const float* Wue = (const float*)d_in[9];
    const int*   src = (const int*)d_in[10];
    const int*   dst = (const int*)d_in[11];
    float* out = (float*)d_out;

    unsigned short* M1   = (unsigned short*)d_ws;                       // 12.8 MB
    unsigned short* Macc = (unsigned short*)((char*)d_ws + (size_t)NN * HD * 2);  // 6.4 MB

    hipMemsetAsync(Macc, 0, (size_t)NN * DNODE * 2, stream);
    int ntiles = (NN + 31) / 32;  // 1563
    node_kernel<<<(ntiles + 7) / 8, 512, 0, stream>>>(h, Wn1, bn1, Wn2, M1, ntiles);
    edge_kernel<<<512, 512, 0, stream>>>(h, eh, Wue, We1, be1, We2, Wcb, src, dst, M1, Macc);
    combine_kernel<<<(NN * DNODE / 8 + 255) / 256, 256, 0, stream>>>(h, Macc, out);
}

// Round 5
// 431.429 us; speedup vs baseline: 1.2135x; 1.1080x over previous
//
#include <hip/hip_runtime.h>
#include <hip/hip_bf16.h>

#define NN 50000
#define NE 800000
#define DNODE 64
#define HD 128

typedef __attribute__((ext_vector_type(8)))  short bf16x8;   // 8 bf16 (4 VGPRs)
typedef __attribute__((ext_vector_type(16))) float f32x16;   // MFMA C/D
typedef __attribute__((ext_vector_type(4)))  float f32x4;
typedef __attribute__((ext_vector_type(4)))  unsigned short u16x4;
typedef __attribute__((ext_vector_type(8)))  unsigned short u16x8;

__device__ __forceinline__ short f2bf(float f) {
    __hip_bfloat16 b = __float2bfloat16(f);
    unsigned short u;
    __builtin_memcpy(&u, &b, 2);
    return (short)u;
}
__device__ __forceinline__ float bf2f(unsigned short s) {
    return __uint_as_float(((unsigned)s) << 16);
}
__device__ __forceinline__ f32x16 zero16() {
    f32x16 z;
#pragma unroll
    for (int i = 0; i < 16; ++i) z[i] = 0.f;
    return z;
}

__device__ __forceinline__ unsigned cvt_pk(float lo, float hi) {
    unsigned r;
    asm("v_cvt_pk_bf16_f32 %0, %1, %2" : "=v"(r) : "v"(lo), "v"(hi));
    return r;
}

// HW packed bf16 atomic add: mem[addr] += lo16, mem[addr+2] += hi16.
__device__ __forceinline__ void atomic_pk_bf16(unsigned short* addr, unsigned data) {
    unsigned long long a = (unsigned long long)(uintptr_t)addr;
    asm volatile("global_atomic_pk_add_bf16 %0, %1, off" :: "v"(a), "v"(data) : "memory");
}

// C/D-domain (16 f32, vals[4m+j] = Y[8m+4hh+j, la]) -> B/A frag. Verified r3.
__device__ __forceinline__ bf16x8 pack_swap(const float* v) {
    unsigned w0 = cvt_pk(v[0], v[1]);
    unsigned w1 = cvt_pk(v[2], v[3]);
    unsigned w2 = cvt_pk(v[4], v[5]);
    unsigned w3 = cvt_pk(v[6], v[7]);
    asm("v_permlane32_swap_b32 %0, %1" : "+v"(w0), "+v"(w2));
    asm("v_permlane32_swap_b32 %0, %1" : "+v"(w1), "+v"(w3));
    union { unsigned u[4]; bf16x8 f; } o;
    o.u[0] = w0; o.u[1] = w1; o.u[2] = w2; o.u[3] = w3;
    return o.f;
}

// Weight W [K x ncols] f32 row-major -> MFMA frags in LDS.
// Frag (ct, ks): lane l, elem j: k = 16ks + 8*(l>>5) + j, col = 32ct + (l&31).
__device__ __forceinline__ void build_frags(const float* __restrict__ W, int ncols,
                                            int nks, int nct, bf16x8* dst,
                                            int tid, int nthr) {
    int total = nct * nks * 64;
    for (int p = tid; p < total; p += nthr) {
        int fi = p >> 6, l = p & 63;
        int ct = fi / nks, ks = fi - ct * nks;
        int col = 32 * ct + (l & 31);
        int kb  = 16 * ks + 8 * (l >> 5);
        bf16x8 v;
#pragma unroll
        for (int j = 0; j < 8; ++j) v[j] = f2bf(W[(size_t)(kb + j) * ncols + col]);
        dst[p] = v;
    }
}

// -------- node precompute: hb16 = bf16(h); M1 = relu(h@Wn1+b)@Wn2 (frag-major) --------
__global__ __launch_bounds__(512, 4) void node_kernel(
        const float* __restrict__ h, const float* __restrict__ Wn1,
        const float* __restrict__ bn1, const float* __restrict__ Wn2,
        unsigned short* __restrict__ M1, unsigned short* __restrict__ hb16,
        int ntiles) {
    __shared__ bf16x8 fWn1[16 * 64];
    __shared__ bf16x8 fWn2[32 * 64];
    __shared__ float  bias[HD];

    int tid = threadIdx.x;
    build_frags(Wn1, HD, 4, 4, fWn1, tid, 512);
    build_frags(Wn2, HD, 8, 4, fWn2, tid, 512);
    if (tid < HD) bias[tid] = bn1[tid];
    __syncthreads();

    int wv = tid >> 6, lane = tid & 63;
    int la = lane & 31, hh = lane >> 5;

    int tile = blockIdx.x * 8 + wv;
    if (tile >= ntiles) return;
    int n0 = tile * 32;
    int n_la = n0 + la;
    int nc = n_la < NN ? n_la : NN - 1;

    bf16x8 hfrag[4];
#pragma unroll
    for (int ks = 0; ks < 4; ++ks) {
        int cb = 16 * ks + 8 * hh;
        f32x4 h0 = *(const f32x4*)&h[(size_t)nc * DNODE + cb];
        f32x4 h1 = *(const f32x4*)&h[(size_t)nc * DNODE + cb + 4];
        union { unsigned u[4]; bf16x8 f; u16x8 s; } xf;
        xf.u[0] = cvt_pk(h0[0], h0[1]);
        xf.u[1] = cvt_pk(h0[2], h0[3]);
        xf.u[2] = cvt_pk(h1[0], h1[1]);
        xf.u[3] = cvt_pk(h1[2], h1[3]);
        hfrag[ks] = xf.f;
        if (n_la < NN)   // bf16 feature row: elem c at byte 2c; chunk = cols cb..cb+7
            *(u16x8*)((char*)hb16 + (size_t)n_la * 128 + 32 * ks + 16 * hh) = xf.s;
    }

    // stage 1 (swapped): T^T = Wn1^T . X^T ; bias+relu ; pack
    bf16x8 tfrag[8];
#pragma unroll
    for (int ct = 0; ct < 4; ++ct) {
        f32x16 acc = zero16();
#pragma unroll
        for (int ks = 0; ks < 4; ++ks)
            acc = __builtin_amdgcn_mfma_f32_32x32x16_bf16(fWn1[(ct * 4 + ks) * 64 + lane], hfrag[ks], acc, 0, 0, 0);
        float vals[16];
#pragma unroll
        for (int m = 0; m < 4; ++m) {
            f32x4 bv = *(const f32x4*)&bias[32 * ct + 8 * m + 4 * hh];
#pragma unroll
            for (int j = 0; j < 4; ++j)
                vals[4 * m + j] = fmaxf(acc[4 * m + j] + bv[j], 0.f);
        }
        tfrag[2 * ct]     = pack_swap(&vals[0]);
        tfrag[2 * ct + 1] = pack_swap(&vals[8]);
    }

    // stage 2 (normal): M1 = T @ Wn2 ; store frag-major:
    // col c=32ct+la -> elem offset hh'*64 + ct*16 + m'*4 + j'  (hh'=(la>>2)&1, m'=la>>3, j'=la&3)
    int moff = ((la >> 2) & 1) * 64 + (la >> 3) * 4 + (la & 3);
#pragma unroll
    for (int ct = 0; ct < 4; ++ct) {
        f32x16 acc = zero16();
#pragma unroll
        for (int ks = 0; ks < 8; ++ks)
            acc = __builtin_amdgcn_mfma_f32_32x32x16_bf16(tfrag[ks], fWn2[(ct * 8 + ks) * 64 + lane], acc, 0, 0, 0);
#pragma unroll
        for (int r = 0; r < 16; ++r) {
            int row = (r & 3) + 8 * (r >> 2) + 4 * hh;
            int node = n0 + row;
            if (node < NN)
                M1[(size_t)node * HD + moff + ct * 16] = (unsigned short)f2bf(acc[r]);
        }
    }
}

// -------- edge kernel: pipelined per-edge chain, 32 edges/wave-tile --------
__global__ __launch_bounds__(768, 3) void edge_kernel(
        const unsigned short* __restrict__ hb16, const float* __restrict__ eh,
        const float* __restrict__ Wue, const float* __restrict__ We1,
        const float* __restrict__ be1, const float* __restrict__ We2,
        const float* __restrict__ Wcb, const int* __restrict__ src,
        const int* __restrict__ dst, const unsigned short* __restrict__ M1,
        unsigned short* __restrict__ Macc) {
    __shared__ bf16x8 fUe[8 * 64];
    __shared__ bf16x8 fE1[16 * 64];
    __shared__ bf16x8 fE2[32 * 64];
    __shared__ bf16x8 fCb[16 * 64];
    __shared__ float  bias[HD];        // 72.5 KB -> 1 block/CU at 768 thr

    int tid = threadIdx.x;
    build_frags(Wue, 64, 4, 2, fUe, tid, 768);
    build_frags(We1, HD, 4, 4, fE1, tid, 768);
    build_frags(We2, HD, 8, 4, fE2, tid, 768);
    build_frags(Wcb, 64, 8, 2, fCb, tid, 768);
    if (tid < HD) bias[tid] = be1[tid];
    __syncthreads();

    int wv = tid >> 6, lane = tid & 63;
    int la = lane & 31, hh = lane >> 5;

    const int NT = NE / 32;                    // 25000
    const int NW = 3072;                       // 256 blocks x 12 waves
    int gw = blockIdx.x * 12 + wv;
    int t0 = (int)(((long long)gw * NT) / NW);
    int t1 = (int)(((long long)(gw + 1) * NT) / NW);
    if (t0 >= t1) return;

    const char* hb = (const char*)hb16;

    // prologue: indices for t0, t0+1; gathers for t0
    int srcA = src[t0 * 32 + la], dstA = dst[t0 * 32 + la];
    int tB = (t0 + 1 < t1) ? t0 + 1 : t0;
    int srcB = src[tB * 32 + la], dstB = dst[tB * 32 + la];
    u16x8 hsA[4], hdA[4];
#pragma unroll
    for (int ks = 0; ks < 4; ++ks) {
        hsA[ks] = *(const u16x8*)(hb + (size_t)srcA * 128 + 32 * ks + 16 * hh);
        hdA[ks] = *(const u16x8*)(hb + (size_t)dstA * 128 + 32 * ks + 16 * hh);
    }

    for (int t = t0; t < t1; ++t) {
        int e_la = t * 32 + la;

        // early-issue current tile: M1 frags (consumed at M2) + eh (consumed at U-epilogue)
        u16x8 mqv[8];
        const char* m1b = (const char*)M1 + (size_t)srcA * 256 + hh * 128;
#pragma unroll
        for (int q = 0; q < 8; ++q)
            mqv[q] = *(const u16x8*)(m1b + 16 * q);
        f32x4 ehq[8];
#pragma unroll
        for (int ct = 0; ct < 2; ++ct)
#pragma unroll
            for (int m = 0; m < 4; ++m)
                ehq[4 * ct + m] = *(const f32x4*)&eh[(size_t)e_la * 64 + 32 * ct + 8 * m + 4 * hh];
        // indices two tiles ahead
        int tC = (t + 2 < t1) ? t + 2 : t1 - 1;
        int srcC = src[tC * 32 + la], dstC = dst[tC * 32 + la];

        // ---- stage U (swapped): U^T = Wue^T . (hs.*hd)^T  (bf16 product) ----
        f32x16 accU0 = zero16(), accU1 = zero16();
#pragma unroll
        for (int ks = 0; ks < 4; ++ks) {
            union { unsigned u[4]; bf16x8 f; } xf;
#pragma unroll
            for (int i = 0; i < 4; ++i) {
                float a0 = bf2f(hsA[ks][2 * i])     * bf2f(hdA[ks][2 * i]);
                float a1 = bf2f(hsA[ks][2 * i + 1]) * bf2f(hdA[ks][2 * i + 1]);
                xf.u[i] = cvt_pk(a0, a1);
            }
            accU0 = __builtin_amdgcn_mfma_f32_32x32x16_bf16(fUe[(0 * 4 + ks) * 64 + lane], xf.f, accU0, 0, 0, 0);
            accU1 = __builtin_amdgcn_mfma_f32_32x32x16_bf16(fUe[(1 * 4 + ks) * 64 + lane], xf.f, accU1, 0, 0, 0);
        }

        // ---- U epilogue: ehn = 0.8 eh + 0.2 U ; pack -> efrag ----
        bf16x8 efrag[4];
#pragma unroll
        for (int ct = 0; ct < 2; ++ct) {
            const f32x16& aU = ct ? accU1 : accU0;
            float vals[16];
#pragma unroll
            for (int m = 0; m < 4; ++m)
#pragma unroll
                for (int j = 0; j < 4; ++j)
                    vals[4 * m + j] = 0.8f * ehq[4 * ct + m][j] + 0.2f * aU[4 * m + j];
            efrag[2 * ct]     = pack_swap(&vals[0]);
            efrag[2 * ct + 1] = pack_swap(&vals[8]);
        }

        // ---- issue next tile's h gathers (before atomics in program order) ----
#pragma unroll
        for (int ks = 0; ks < 4; ++ks) {
            hsA[ks] = *(const u16x8*)(hb + (size_t)srcB * 128 + 32 * ks + 16 * hh);
            hdA[ks] = *(const u16x8*)(hb + (size_t)dstB * 128 + 32 * ks + 16 * hh);
        }

        // ---- stage T2 (swapped): relu(ehn @ We1 + b) -> tfrag ----
        bf16x8 tfrag[8];
#pragma unroll
        for (int ct = 0; ct < 4; ++ct) {
            f32x16 acc = zero16();
#pragma unroll
            for (int ks = 0; ks < 4; ++ks)
                acc = __builtin_amdgcn_mfma_f32_32x32x16_bf16(fE1[(ct * 4 + ks) * 64 + lane], efrag[ks], acc, 0, 0, 0);
            float vals[16];
#pragma unroll
            for (int m = 0; m < 4; ++m) {
                f32x4 bv = *(const f32x4*)&bias[32 * ct + 8 * m + 4 * hh];
#pragma unroll
                for (int j = 0; j < 4; ++j)
                    vals[4 * m + j] = fmaxf(acc[4 * m + j] + bv[j], 0.f);
            }
            tfrag[2 * ct]     = pack_swap(&vals[0]);
            tfrag[2 * ct + 1] = pack_swap(&vals[8]);
        }

        // ---- stage M2 (swapped): M2 = T2 @ We2 ; P = M1 .* M2 ; pack -> pfrag ----
        bf16x8 pfrag[8];
#pragma unroll
        for (int ct = 0; ct < 4; ++ct) {
            f32x16 acc = zero16();
#pragma unroll
            for (int ks = 0; ks < 8; ++ks)
                acc = __builtin_amdgcn_mfma_f32_32x32x16_bf16(fE2[(ct * 8 + ks) * 64 + lane], tfrag[ks], acc, 0, 0, 0);
            float vals[16];
#pragma unroll
            for (int m = 0; m < 4; ++m) {
                u16x8 Q = mqv[2 * ct + (m >> 1)];
#pragma unroll
                for (int j = 0; j < 4; ++j)
                    vals[4 * m + j] = acc[4 * m + j] * bf2f(Q[(m & 1) * 4 + j]);
            }
            pfrag[2 * ct]     = pack_swap(&vals[0]);
            pfrag[2 * ct + 1] = pack_swap(&vals[8]);
        }

        // dst rows for scatter (current tile)
        int dstR[16];
#pragma unroll
        for (int r = 0; r < 16; ++r)
            dstR[r] = __shfl(dstA, (r & 3) + 8 * (r >> 2) + 4 * hh);

        // ---- stage F (normal): m = tanh(P @ Wcb) ; packed bf16 atomic scatter ----
        f32x16 accF0 = zero16(), accF1 = zero16();
#pragma unroll
        for (int ks = 0; ks < 8; ++ks) {
            accF0 = __builtin_amdgcn_mfma_f32_32x32x16_bf16(pfrag[ks], fCb[(0 * 8 + ks) * 64 + lane], accF0, 0, 0, 0);
            accF1 = __builtin_amdgcn_mfma_f32_32x32x16_bf16(pfrag[ks], fCb[(1 * 8 + ks) * 64 + lane], accF1, 0, 0, 0);
        }
        int odd = lane & 1;
#pragma unroll
        for (int r = 0; r < 16; ++r) {
            float x0 = fminf(fmaxf(accF0[r], -10.f), 10.f);
            float x1 = fminf(fmaxf(accF1[r], -10.f), 10.f);
            float ex0 = __expf(2.f * x0), ex1 = __expf(2.f * x1);
            float m0 = (ex0 - 1.f) * __builtin_amdgcn_rcpf(ex0 + 1.f);
            float m1 = (ex1 - 1.f) * __builtin_amdgcn_rcpf(ex1 + 1.f);
            float e0 = __shfl_xor(m0, 1);
            float e1 = __shfl_xor(m1, 1);
            unsigned w = odd ? cvt_pk(e1, m1) : cvt_pk(m0, e0);
            int colstart = odd ? (31 + la) : la;
            atomic_pk_bf16(&Macc[(size_t)dstR[r] * 64 + colstart], w);
        }

        srcA = srcB; dstA = dstB; srcB = srcC; dstB = dstC;
    }
}

// -------- combine: out = h + Macc --------
__global__ __launch_bounds__(256) void combine_kernel(
        const float* __restrict__ h, const unsigned short* __restrict__ Macc,
        float* __restrict__ out) {
    int i = (blockIdx.x * 256 + threadIdx.x) * 8;
    if (i >= NN * DNODE) return;
    u16x8 mv = *(const u16x8*)&Macc[i];
    f32x4 h0 = *(const f32x4*)&h[i];
    f32x4 h1 = *(const f32x4*)&h[i + 4];
    f32x4 o0, o1;
#pragma unroll
    for (int j = 0; j < 4; ++j) {
        o0[j] = h0[j] + bf2f(mv[j]);
        o1[j] = h1[j] + bf2f(mv[4 + j]);
    }
    *(f32x4*)&out[i]     = o0;
    *(f32x4*)&out[i + 4] = o1;
}

extern "C" void kernel_launch(void* const* d_in, const int* in_sizes, int n_in,
                              void* d_out, int out_size, void* d_ws, size_t ws_size,
                              hipStream_t stream) {
    const float* h   = (const float*)d_in[0];
    const float* eh  = (const float*)d_in[1];
    const float* Wn1 = (const float*)d_in[2];
    const float* bn1 = (const float*)d_in[3];
    const float* Wn2 = (const float*)d_in[4];
    const float* We1 = (const float*)d_in[5];
    const float* be1 = (const float*)d_in[6];
    const float* We2 = (const float*)d_in[7];
    const float* Wcb = (const float*)d_in[8];
    const float* Wue = (const float*)d_in[9];
    const int*   src = (const int*)d_in[10];
    const int*   dst = (const int*)d_in[11];
    float* out = (float*)d_out;

    unsigned short* M1   = (unsigned short*)d_ws;                                   // 12.8 MB
    unsigned short* Macc = (unsigned short*)((char*)d_ws + (size_t)NN * HD * 2);    //  6.4 MB
    unsigned short* hb16 = (unsigned short*)((char*)d_ws + (size_t)NN * (HD + DNODE) * 2); // 6.4 MB

    hipMemsetAsync(Macc, 0, (size_t)NN * DNODE * 2, stream);
    int ntiles = (NN + 31) / 32;  // 1563
    node_kernel<<<(ntiles + 7) / 8, 512, 0, stream>>>(h, Wn1, bn1, Wn2, M1, hb16, ntiles);
    edge_kernel<<<256, 768, 0, stream>>>(hb16, eh, Wue, We1, be1, We2, Wcb, src, dst, M1, Macc);
    combine_kernel<<<(NN * DNODE / 8 + 255) / 256, 256, 0, stream>>>(h, Macc, out);
}